// Round 3
// baseline (117.043 us; speedup 1.0000x reference)
//
#include <hip/hip_runtime.h>
#include <math.h>

#define NV 1000000
#define NC 4000000
#define NGROUP (NC / 4)   // 4 clauses per thread
#define TPB 256

typedef _Float16 half_t;
typedef _Float16 half4_t __attribute__((ext_vector_type(4)));
typedef int   vint4  __attribute__((ext_vector_type(4)));
typedef float vfloat4 __attribute__((ext_vector_type(4)));

__device__ __forceinline__ float sigf(float x) { return 1.0f / (1.0f + __expf(-x)); }

// Kernel 1: assignments (f32) + fp16 sigmoid gather-table + scalar init
__global__ __launch_bounds__(TPB) void sat_sigmoid(
    const float* __restrict__ logits,
    float* __restrict__ out,        // [0,NV) assignments | scalars at NV+NC
    half_t* __restrict__ tbl,       // [NV] fp16 sigmoid table (may be null)
    int write_tbl)
{
    const int i = blockIdx.x * TPB + threadIdx.x;
    if (i == 0) {  // seed reduction scalars (d_out is never re-poisoned between replays)
        out[NV + NC]     = INFINITY;
        out[NV + NC + 1] = 0.0f;
    }
    if (i < NV / 4) {
        vfloat4 v = ((const vfloat4*)logits)[i];
        vfloat4 r;
        r.x = sigf(v.x); r.y = sigf(v.y); r.z = sigf(v.z); r.w = sigf(v.w);
        ((vfloat4*)out)[i] = r;
        if (write_tbl) {
            half4_t h;
            h.x = (half_t)r.x; h.y = (half_t)r.y; h.z = (half_t)r.z; h.w = (half_t)r.w;
            ((half4_t*)tbl)[i] = h;
        }
    }
}

// literal value from gathered raw value
template <bool USE_TBL>
__device__ __forceinline__ float litv(float g, int s) {
    if (USE_TBL) return s ? g : 1.0f - g;          // g = sigmoid(x) from fp16 table
    float x = s ? g : -g;                          // g = raw logit
    return sigf(x);
}

template <bool USE_TBL>
__global__ __launch_bounds__(TPB) void sat_clauses(
    const float*  __restrict__ logits,
    const half_t* __restrict__ tbl,
    const vint4*  __restrict__ vars4,
    const vint4*  __restrict__ signs4,
    float* __restrict__ out)
{
    const int g = blockIdx.x * TPB + threadIdx.x;
    float minv = INFINITY;
    float fcnt = 0.0f;

    if (g < NGROUP) {
        // 6 coalesced nontemporal 16B loads (streaming: keep out of L2)
        vint4 a  = __builtin_nontemporal_load(&vars4[3 * g]);
        vint4 b  = __builtin_nontemporal_load(&vars4[3 * g + 1]);
        vint4 c  = __builtin_nontemporal_load(&vars4[3 * g + 2]);
        vint4 sa = __builtin_nontemporal_load(&signs4[3 * g]);
        vint4 sb = __builtin_nontemporal_load(&signs4[3 * g + 1]);
        vint4 sc = __builtin_nontemporal_load(&signs4[3 * g + 2]);

        // 12 independent scattered gathers, all issued before any use
        float v0, v1, v2, v3, v4, v5, v6, v7, v8, v9, v10, v11;
        if (USE_TBL) {
            v0  = (float)tbl[a.x]; v1  = (float)tbl[a.y]; v2  = (float)tbl[a.z];
            v3  = (float)tbl[a.w]; v4  = (float)tbl[b.x]; v5  = (float)tbl[b.y];
            v6  = (float)tbl[b.z]; v7  = (float)tbl[b.w]; v8  = (float)tbl[c.x];
            v9  = (float)tbl[c.y]; v10 = (float)tbl[c.z]; v11 = (float)tbl[c.w];
        } else {
            v0  = logits[a.x]; v1  = logits[a.y]; v2  = logits[a.z];
            v3  = logits[a.w]; v4  = logits[b.x]; v5  = logits[b.y];
            v6  = logits[b.z]; v7  = logits[b.w]; v8  = logits[c.x];
            v9  = logits[c.y]; v10 = logits[c.z]; v11 = logits[c.w];
        }

        vfloat4 r;
        r.x = fmaxf(fmaxf(litv<USE_TBL>(v0, sa.x),  litv<USE_TBL>(v1, sa.y)),
                    litv<USE_TBL>(v2, sa.z));
        r.y = fmaxf(fmaxf(litv<USE_TBL>(v3, sa.w),  litv<USE_TBL>(v4, sb.x)),
                    litv<USE_TBL>(v5, sb.y));
        r.z = fmaxf(fmaxf(litv<USE_TBL>(v6, sb.z),  litv<USE_TBL>(v7, sb.w)),
                    litv<USE_TBL>(v8, sc.x));
        r.w = fmaxf(fmaxf(litv<USE_TBL>(v9, sc.y),  litv<USE_TBL>(v10, sc.z)),
                    litv<USE_TBL>(v11, sc.w));

        __builtin_nontemporal_store(r, (vfloat4*)(out + NV) + g);

        minv = fminf(fminf(r.x, r.y), fminf(r.z, r.w));
        fcnt = (float)((r.x > 0.5f) + (r.y > 0.5f) + (r.z > 0.5f) + (r.w > 0.5f));
    }

    // wave + block reduction (all threads participate; idle threads hold INF/0)
    #pragma unroll
    for (int off = 32; off > 0; off >>= 1) {
        minv = fminf(minv, __shfl_down(minv, off));
        fcnt += __shfl_down(fcnt, off);
    }
    __shared__ float smin[TPB / 64];
    __shared__ float scnt[TPB / 64];
    const int wave = threadIdx.x >> 6, lane = threadIdx.x & 63;
    if (lane == 0) { smin[wave] = minv; scnt[wave] = fcnt; }
    __syncthreads();
    if (threadIdx.x == 0) {
        float m = smin[0], s = scnt[0];
        #pragma unroll
        for (int w = 1; w < TPB / 64; ++w) { m = fminf(m, smin[w]); s += scnt[w]; }
        // all satisfaction values are > 0 → uint ordering == float ordering
        atomicMin((unsigned int*)(out + NV + NC), __float_as_uint(m));
        atomicAdd(out + NV + NC + 1, s);   // integer-valued: exact, order-independent
    }
}

extern "C" void kernel_launch(void* const* d_in, const int* in_sizes, int n_in,
                              void* d_out, int out_size, void* d_ws, size_t ws_size,
                              hipStream_t stream) {
    const float* logits = (const float*)d_in[0];
    const vint4* vars4  = (const vint4*)d_in[1];
    const vint4* signs4 = (const vint4*)d_in[2];
    float* out = (float*)d_out;
    half_t* tbl = (half_t*)d_ws;

    const bool use_tbl = ws_size >= (size_t)NV * sizeof(half_t);

    const int blkA = (NV / 4 + TPB - 1) / TPB;
    sat_sigmoid<<<blkA, TPB, 0, stream>>>(logits, out, tbl, use_tbl ? 1 : 0);

    const int blkB = (NGROUP + TPB - 1) / TPB;
    if (use_tbl)
        sat_clauses<true><<<blkB, TPB, 0, stream>>>(logits, tbl, vars4, signs4, out);
    else
        sat_clauses<false><<<blkB, TPB, 0, stream>>>(logits, tbl, vars4, signs4, out);
}

// Round 4
// 75.194 us; speedup vs baseline: 1.5565x; 1.5565x over previous
//
#include <hip/hip_runtime.h>
#include <math.h>

#define NV 1000000
#define NC 4000000
#define NGROUP (NC / 4)    // 1,000,000 groups of 4 clauses
#define G2 (NGROUP / 2)    // two groups per thread
#define TPB 256

typedef _Float16 half_t;
typedef _Float16 half4_t __attribute__((ext_vector_type(4)));
typedef int   vint4   __attribute__((ext_vector_type(4)));
typedef float vfloat4 __attribute__((ext_vector_type(4)));

__device__ __forceinline__ float sigf(float x) { return 1.0f / (1.0f + __expf(-x)); }

// Kernel 1: assignments (f32) + fp16 sigmoid gather-table + scalar init
__global__ __launch_bounds__(TPB) void sat_sigmoid(
    const float* __restrict__ logits,
    float* __restrict__ out,        // [0,NV) assignments | scalars at NV+NC
    half_t* __restrict__ tbl)
{
    const int i = blockIdx.x * TPB + threadIdx.x;
    if (i == 0) {  // seed reduction scalars (d_out is never re-poisoned between replays)
        out[NV + NC]     = INFINITY;
        out[NV + NC + 1] = 0.0f;
    }
    if (i < NV / 4) {
        vfloat4 v = ((const vfloat4*)logits)[i];
        vfloat4 r;
        r.x = sigf(v.x); r.y = sigf(v.y); r.z = sigf(v.z); r.w = sigf(v.w);
        ((vfloat4*)out)[i] = r;
        half4_t h;
        h.x = (half_t)r.x; h.y = (half_t)r.y; h.z = (half_t)r.z; h.w = (half_t)r.w;
        ((half4_t*)tbl)[i] = h;
    }
}

__device__ __forceinline__ float litv(float sg, int s) { return s ? sg : 1.0f - sg; }

// Each thread: 2 clause-groups (8 clauses), 24 independent gathers in flight.
__global__ __launch_bounds__(TPB) void sat_clauses(
    const half_t* __restrict__ tbl,
    const vint4*  __restrict__ vars4,
    const vint4*  __restrict__ signs4,
    float* __restrict__ out)
{
    const int g = blockIdx.x * TPB + threadIdx.x;
    float minv = INFINITY;
    float fcnt = 0.0f;

    if (g < G2) {
        const int h = g + G2;
        // 12 coalesced index loads (plain: allow L2/L3 retention)
        vint4 a0 = vars4[3 * g],  a1 = vars4[3 * g + 1],  a2 = vars4[3 * g + 2];
        vint4 b0 = vars4[3 * h],  b1 = vars4[3 * h + 1],  b2 = vars4[3 * h + 2];
        vint4 sa0 = signs4[3 * g], sa1 = signs4[3 * g + 1], sa2 = signs4[3 * g + 2];
        vint4 sb0 = signs4[3 * h], sb1 = signs4[3 * h + 1], sb2 = signs4[3 * h + 2];

        // 24 independent scattered gathers, all issued before any use
        float u0  = (float)tbl[a0.x], u1  = (float)tbl[a0.y], u2  = (float)tbl[a0.z];
        float u3  = (float)tbl[a0.w], u4  = (float)tbl[a1.x], u5  = (float)tbl[a1.y];
        float u6  = (float)tbl[a1.z], u7  = (float)tbl[a1.w], u8  = (float)tbl[a2.x];
        float u9  = (float)tbl[a2.y], u10 = (float)tbl[a2.z], u11 = (float)tbl[a2.w];
        float w0  = (float)tbl[b0.x], w1  = (float)tbl[b0.y], w2  = (float)tbl[b0.z];
        float w3  = (float)tbl[b0.w], w4  = (float)tbl[b1.x], w5  = (float)tbl[b1.y];
        float w6  = (float)tbl[b1.z], w7  = (float)tbl[b1.w], w8  = (float)tbl[b2.x];
        float w9  = (float)tbl[b2.y], w10 = (float)tbl[b2.z], w11 = (float)tbl[b2.w];

        vfloat4 r, q;
        r.x = fmaxf(fmaxf(litv(u0, sa0.x), litv(u1,  sa0.y)), litv(u2,  sa0.z));
        r.y = fmaxf(fmaxf(litv(u3, sa0.w), litv(u4,  sa1.x)), litv(u5,  sa1.y));
        r.z = fmaxf(fmaxf(litv(u6, sa1.z), litv(u7,  sa1.w)), litv(u8,  sa2.x));
        r.w = fmaxf(fmaxf(litv(u9, sa2.y), litv(u10, sa2.z)), litv(u11, sa2.w));
        q.x = fmaxf(fmaxf(litv(w0, sb0.x), litv(w1,  sb0.y)), litv(w2,  sb0.z));
        q.y = fmaxf(fmaxf(litv(w3, sb0.w), litv(w4,  sb1.x)), litv(w5,  sb1.y));
        q.z = fmaxf(fmaxf(litv(w6, sb1.z), litv(w7,  sb1.w)), litv(w8,  sb2.x));
        q.w = fmaxf(fmaxf(litv(w9, sb2.y), litv(w10, sb2.z)), litv(w11, sb2.w));

        __builtin_nontemporal_store(r, (vfloat4*)(out + NV) + g);
        __builtin_nontemporal_store(q, (vfloat4*)(out + NV) + h);

        minv = fminf(fminf(fminf(r.x, r.y), fminf(r.z, r.w)),
                     fminf(fminf(q.x, q.y), fminf(q.z, q.w)));
        fcnt = (float)((r.x > 0.5f) + (r.y > 0.5f) + (r.z > 0.5f) + (r.w > 0.5f) +
                       (q.x > 0.5f) + (q.y > 0.5f) + (q.z > 0.5f) + (q.w > 0.5f));
    }

    // wave + block reduction (idle threads hold INF/0)
    #pragma unroll
    for (int off = 32; off > 0; off >>= 1) {
        minv = fminf(minv, __shfl_down(minv, off));
        fcnt += __shfl_down(fcnt, off);
    }
    __shared__ float smin[TPB / 64];
    __shared__ float scnt[TPB / 64];
    const int wave = threadIdx.x >> 6, lane = threadIdx.x & 63;
    if (lane == 0) { smin[wave] = minv; scnt[wave] = fcnt; }
    __syncthreads();
    if (threadIdx.x == 0) {
        float m = smin[0], s = scnt[0];
        #pragma unroll
        for (int w = 1; w < TPB / 64; ++w) { m = fminf(m, smin[w]); s += scnt[w]; }
        // all satisfaction values are > 0 → uint ordering == float ordering
        atomicMin((unsigned int*)(out + NV + NC), __float_as_uint(m));
        atomicAdd(out + NV + NC + 1, s);   // integer-valued: exact, order-independent
    }
}

extern "C" void kernel_launch(void* const* d_in, const int* in_sizes, int n_in,
                              void* d_out, int out_size, void* d_ws, size_t ws_size,
                              hipStream_t stream) {
    const float* logits = (const float*)d_in[0];
    const vint4* vars4  = (const vint4*)d_in[1];
    const vint4* signs4 = (const vint4*)d_in[2];
    float* out = (float*)d_out;
    half_t* tbl = (half_t*)d_ws;   // 2 MB, ws_size is ample

    const int blkA = (NV / 4 + TPB - 1) / TPB;
    sat_sigmoid<<<blkA, TPB, 0, stream>>>(logits, out, tbl);

    const int blkB = (G2 + TPB - 1) / TPB;
    sat_clauses<<<blkB, TPB, 0, stream>>>(tbl, vars4, signs4, out);
}

// Round 5
// 75.057 us; speedup vs baseline: 1.5594x; 1.0018x over previous
//
#include <hip/hip_runtime.h>
#include <math.h>

#define NV 1000000
#define NC 4000000
#define NGROUP (NC / 4)    // 1,000,000 groups of 4 clauses
#define G4 (NGROUP / 4)    // four groups per thread
#define TPB 256

typedef _Float16 half_t;
typedef _Float16 half4_t __attribute__((ext_vector_type(4)));
typedef int   vint4   __attribute__((ext_vector_type(4)));
typedef float vfloat4 __attribute__((ext_vector_type(4)));

__device__ __forceinline__ float sigf(float x) { return 1.0f / (1.0f + __expf(-x)); }

// Kernel 1: assignments (f32) + fp16 sigmoid gather-table + scalar init
__global__ __launch_bounds__(TPB) void sat_sigmoid(
    const float* __restrict__ logits,
    float* __restrict__ out,        // [0,NV) assignments | scalars at NV+NC
    half_t* __restrict__ tbl)
{
    const int i = blockIdx.x * TPB + threadIdx.x;
    if (i == 0) {  // seed reduction scalars (d_out is never re-poisoned between replays)
        out[NV + NC]     = INFINITY;
        out[NV + NC + 1] = 0.0f;
    }
    if (i < NV / 4) {
        vfloat4 v = ((const vfloat4*)logits)[i];
        vfloat4 r;
        r.x = sigf(v.x); r.y = sigf(v.y); r.z = sigf(v.z); r.w = sigf(v.w);
        ((vfloat4*)out)[i] = r;
        half4_t h;
        h.x = (half_t)r.x; h.y = (half_t)r.y; h.z = (half_t)r.z; h.w = (half_t)r.w;
        ((half4_t*)tbl)[i] = h;
    }
}

__device__ __forceinline__ float litv(float sg, int s) { return s ? sg : 1.0f - sg; }

// Each thread: 4 clause-groups (16 clauses), 48 independent gathers in flight.
__global__ __launch_bounds__(TPB) void sat_clauses(
    const half_t* __restrict__ tbl,
    const vint4*  __restrict__ vars4,
    const vint4*  __restrict__ signs4,
    float* __restrict__ out)
{
    const int g0 = blockIdx.x * TPB + threadIdx.x;
    float minv = INFINITY;
    float fcnt = 0.0f;

    if (g0 < G4) {
        int gid[4];
        #pragma unroll
        for (int k = 0; k < 4; ++k) gid[k] = g0 + k * G4;

        // 12 coalesced index loads for vars (issue first: gathers depend on them)
        vint4 va[4][3];
        #pragma unroll
        for (int k = 0; k < 4; ++k)
            #pragma unroll
            for (int j = 0; j < 3; ++j)
                va[k][j] = vars4[3 * gid[k] + j];

        // 48 independent scattered gathers, all issued before any use
        half_t hv[4][12];
        #pragma unroll
        for (int k = 0; k < 4; ++k) {
            hv[k][0]  = tbl[va[k][0].x]; hv[k][1]  = tbl[va[k][0].y];
            hv[k][2]  = tbl[va[k][0].z]; hv[k][3]  = tbl[va[k][0].w];
            hv[k][4]  = tbl[va[k][1].x]; hv[k][5]  = tbl[va[k][1].y];
            hv[k][6]  = tbl[va[k][1].z]; hv[k][7]  = tbl[va[k][1].w];
            hv[k][8]  = tbl[va[k][2].x]; hv[k][9]  = tbl[va[k][2].y];
            hv[k][10] = tbl[va[k][2].z]; hv[k][11] = tbl[va[k][2].w];
        }

        // 12 coalesced sign loads (independent of gathers; overlap their latency)
        vint4 sg[4][3];
        #pragma unroll
        for (int k = 0; k < 4; ++k)
            #pragma unroll
            for (int j = 0; j < 3; ++j)
                sg[k][j] = signs4[3 * gid[k] + j];

        #pragma unroll
        for (int k = 0; k < 4; ++k) {
            vfloat4 r;
            r.x = fmaxf(fmaxf(litv((float)hv[k][0], sg[k][0].x),
                              litv((float)hv[k][1], sg[k][0].y)),
                        litv((float)hv[k][2], sg[k][0].z));
            r.y = fmaxf(fmaxf(litv((float)hv[k][3], sg[k][0].w),
                              litv((float)hv[k][4], sg[k][1].x)),
                        litv((float)hv[k][5], sg[k][1].y));
            r.z = fmaxf(fmaxf(litv((float)hv[k][6], sg[k][1].z),
                              litv((float)hv[k][7], sg[k][1].w)),
                        litv((float)hv[k][8], sg[k][2].x));
            r.w = fmaxf(fmaxf(litv((float)hv[k][9], sg[k][2].y),
                              litv((float)hv[k][10], sg[k][2].z)),
                        litv((float)hv[k][11], sg[k][2].w));

            __builtin_nontemporal_store(r, (vfloat4*)(out + NV) + gid[k]);

            minv = fminf(minv, fminf(fminf(r.x, r.y), fminf(r.z, r.w)));
            fcnt += (float)((r.x > 0.5f) + (r.y > 0.5f) +
                            (r.z > 0.5f) + (r.w > 0.5f));
        }
    }

    // wave + block reduction (idle threads hold INF/0)
    #pragma unroll
    for (int off = 32; off > 0; off >>= 1) {
        minv = fminf(minv, __shfl_down(minv, off));
        fcnt += __shfl_down(fcnt, off);
    }
    __shared__ float smin[TPB / 64];
    __shared__ float scnt[TPB / 64];
    const int wave = threadIdx.x >> 6, lane = threadIdx.x & 63;
    if (lane == 0) { smin[wave] = minv; scnt[wave] = fcnt; }
    __syncthreads();
    if (threadIdx.x == 0) {
        float m = smin[0], s = scnt[0];
        #pragma unroll
        for (int w = 1; w < TPB / 64; ++w) { m = fminf(m, smin[w]); s += scnt[w]; }
        // all satisfaction values are > 0 → uint ordering == float ordering
        atomicMin((unsigned int*)(out + NV + NC), __float_as_uint(m));
        atomicAdd(out + NV + NC + 1, s);   // integer-valued: exact, order-independent
    }
}

extern "C" void kernel_launch(void* const* d_in, const int* in_sizes, int n_in,
                              void* d_out, int out_size, void* d_ws, size_t ws_size,
                              hipStream_t stream) {
    const float* logits = (const float*)d_in[0];
    const vint4* vars4  = (const vint4*)d_in[1];
    const vint4* signs4 = (const vint4*)d_in[2];
    float* out = (float*)d_out;
    half_t* tbl = (half_t*)d_ws;   // 2 MB, ws_size is ample

    const int blkA = (NV / 4 + TPB - 1) / TPB;
    sat_sigmoid<<<blkA, TPB, 0, stream>>>(logits, out, tbl);

    const int blkB = (G4 + TPB - 1) / TPB;
    sat_clauses<<<blkB, TPB, 0, stream>>>(tbl, vars4, signs4, out);
}